// Round 1
// baseline (492.771 us; speedup 1.0000x reference)
//
#include <hip/hip_runtime.h>
#include <math.h>

typedef _Float16 f16x8 __attribute__((ext_vector_type(8)));
typedef _Float16 f16x4 __attribute__((ext_vector_type(4)));
typedef float f32x16 __attribute__((ext_vector_type(16)));

__device__ __forceinline__ void async_copy16(const void* g, void* l) {
    __builtin_amdgcn_global_load_lds(
        (const __attribute__((address_space(1))) void*)g,
        (__attribute__((address_space(3))) void*)l, 16, 0, 0);
}

// ---------------- fused prep: cast x->f16 | build W0t | build W1t ----------------
// blocks 0..1023   : cast (8 float4 / thread)
// blocks 1024..1279: W0t build (o,p) = b-1024
// blocks 1280..1407: W1t build (o,p) = b-1280
__global__ __launch_bounds__(256) void prep_kernel(
    const float* __restrict__ x, _Float16* __restrict__ xh,
    const float* __restrict__ c0a, const float* __restrict__ c0b,
    const float* __restrict__ c0c, _Float16* __restrict__ W0t,
    const float* __restrict__ c1a, const float* __restrict__ c1b,
    const float* __restrict__ c1c, _Float16* __restrict__ W1t) {
    __shared__ float G[16384];
    const int b = blockIdx.x, t = threadIdx.x;
    if (b < 1024) {
        const float4* in4 = (const float4*)x;
        f16x4* out4 = (f16x4*)xh;
        const int base = b * 2048 + t;
#pragma unroll
        for (int u = 0; u < 8; ++u) {
            float4 v = in4[base + u * 256];
            f16x4 o;
            o[0] = (_Float16)v.x; o[1] = (_Float16)v.y;
            o[2] = (_Float16)v.z; o[3] = (_Float16)v.w;
            out4[base + u * 256] = o;
        }
    } else if (b < 1280) {
        const int o = (b - 1024) >> 4, p = (b - 1024) & 15;
        // G[q16][r8][j16][k8] = sum_s c0b[r,j,p,s]*c0c[s,k,q]
#pragma unroll
        for (int n = 0; n < 64; ++n) {
            int idx = t + 256 * n;
            int k = idx & 7, j = (idx >> 3) & 15, r = (idx >> 7) & 7, q = idx >> 10;
            float s = 0.f;
#pragma unroll
            for (int ss = 0; ss < 8; ++ss)
                s += c0b[((r * 16 + j) * 16 + p) * 8 + ss] * c0c[(ss * 8 + k) * 16 + q];
            G[idx] = s;
        }
        __syncthreads();
        const int i = t >> 5, j = (t >> 1) & 15, kq = t & 1;
        float a[8];
#pragma unroll
        for (int r = 0; r < 8; ++r) a[r] = c0a[(i * 16 + o) * 8 + r];
        const float4* G4 = (const float4*)G;
#pragma unroll
        for (int q = 0; q < 16; ++q) {
            float4 acc = {0.f, 0.f, 0.f, 0.f};
#pragma unroll
            for (int r = 0; r < 8; ++r) {
                float4 g = G4[q * 256 + r * 32 + j * 2 + kq];
                acc.x += a[r] * g.x; acc.y += a[r] * g.y;
                acc.z += a[r] * g.z; acc.w += a[r] * g.w;
            }
            f16x4 h4;
            h4[0] = (_Float16)acc.x; h4[1] = (_Float16)acc.y;
            h4[2] = (_Float16)acc.z; h4[3] = (_Float16)acc.w;
            *(f16x4*)(W0t + (size_t)((o * 16 + p) * 16 + q) * 1024 + t * 4) = h4;
        }
    } else {
        const int o = (b - 1280) >> 4, p = (b - 1280) & 15;
        // G[q8][r8][j16][k16] = sum_s c1b[r,j,p,s]*c1c[s,k,q]
#pragma unroll
        for (int n = 0; n < 64; ++n) {
            int idx = t + 256 * n;
            int k = idx & 15, j = (idx >> 4) & 15, r = (idx >> 8) & 7, q = idx >> 11;
            float s = 0.f;
#pragma unroll
            for (int ss = 0; ss < 8; ++ss)
                s += c1b[((r * 16 + j) * 16 + p) * 8 + ss] * c1c[(ss * 16 + k) * 8 + q];
            G[idx] = s;
        }
        __syncthreads();
        const int ig = t >> 6, j = (t >> 2) & 15, kq = t & 3;
        float a[4][8];
#pragma unroll
        for (int ii = 0; ii < 4; ++ii)
#pragma unroll
            for (int r = 0; r < 8; ++r) a[ii][r] = c1a[((ig * 4 + ii) * 8 + o) * 8 + r];
        const float4* G4 = (const float4*)G;
#pragma unroll
        for (int q = 0; q < 8; ++q) {
            float4 acc[4] = {{0,0,0,0},{0,0,0,0},{0,0,0,0},{0,0,0,0}};
#pragma unroll
            for (int r = 0; r < 8; ++r) {
                float4 g = G4[q * 512 + r * 64 + j * 4 + kq];
#pragma unroll
                for (int ii = 0; ii < 4; ++ii) {
                    acc[ii].x += a[ii][r] * g.x; acc[ii].y += a[ii][r] * g.y;
                    acc[ii].z += a[ii][r] * g.z; acc[ii].w += a[ii][r] * g.w;
                }
            }
            const size_t rowbase = (size_t)((o * 16 + p) * 8 + q) * 4096;
#pragma unroll
            for (int ii = 0; ii < 4; ++ii) {
                f16x4 h4;
                h4[0] = (_Float16)acc[ii].x; h4[1] = (_Float16)acc[ii].y;
                h4[2] = (_Float16)acc[ii].z; h4[3] = (_Float16)acc[ii].w;
                *(f16x4*)(W1t + rowbase + (ig * 4 + ii) * 256 + j * 16 + kq * 4) = h4;
            }
        }
    }
}

// ---------------- GEMM: C = A(MxK) * Bt(NxK)^T, BK=64, 32x32x16 MFMA ----------------
// T3-minimal 2-phase double-buffer: stage(next) issued BEFORE compute(cur),
// ONE __syncthreads per K-step (its implicit vmcnt(0)/lgkmcnt(0) drain covers
// both the staging completion and the prior tile's ds_reads).
// LDS layout (k-chunk major, conflict-free): elem = c*1024 + row*8, c=k/8.
//   read: half-wave (32 lanes) reads 32 consecutive rows' 16B at one chunk
//   -> 512B contiguous -> zero bank conflicts (was 4-way with row-major+XOR).
//   stage: thread t, load u -> LDS elem (t+256u)*8, i.e. chunk (t>>7)+2u,
//   row t&127. Wave-uniform dest + lane*16 (global_load_lds requirement),
//   per-lane global source row/chunk. Bijective coverage of 128x8 chunks.
// Wave tile 64x64 = 2x2 of 32x32. A-frag: m=lane&31, k=(lane>>5)*8+j.
// C/D: col=lane&31, row=(reg&3)+8*(reg>>2)+4*(lane>>5).
// OUTMODE 1: f16 C = gelu(acc+bias);  OUTMODE 0: fp32 C = acc+bias
template <int OUTMODE>
__global__ __launch_bounds__(256) void gemm32_kernel(
    const _Float16* __restrict__ A, const _Float16* __restrict__ Bt,
    const float* __restrict__ bias, void* __restrict__ Cout,
    int M, int N, int K) {
    constexpr int BK = 64;
    __shared__ alignas(16) _Float16 sA[2][8192];
    __shared__ alignas(16) _Float16 sB[2][8192];

    const int t = threadIdx.x, lane = t & 63, w = t >> 6;

    // T1: XCD-bijective block swizzle (nwg % 8 == 0 for both launches:
    // 64x32=2048 and 64x8=512). Consecutive swizzled blocks share an n-tile
    // (B-panel) within one XCD's L2.
    const int nwg = gridDim.x * gridDim.y;
    int bid = blockIdx.y * gridDim.x + blockIdx.x;
    bid = (bid & 7) * (nwg >> 3) + (bid >> 3);
    const int m0 = (bid % gridDim.x) * 128;
    const int n0 = (bid / gridDim.x) * 128;

    const int wm = (w & 1) * 64, wn = (w >> 1) * 64;
    const int l31 = lane & 31, lh = lane >> 5;

    f32x16 acc[2][2] = {};

    // staging: thread t handles row r=t&127, chunks (t>>7)+2u, u=0..3
    const int r = t & 127, c0 = t >> 7;
    const _Float16* gA = A + (size_t)(m0 + r) * K + c0 * 8;
    const _Float16* gB = Bt + (size_t)(n0 + r) * K + c0 * 8;
    const int ldst = t * 8;  // element offset of thread's first 16B LDS slot

    // fragment base offsets (elements): + c*1024 per k-chunk, + i*256 per 32 rows
    const int aoff0 = (wm + l31) * 8;
    const int boff0 = (wn + l31) * 8;

    auto stage = [&](int buf, int k0) {
#pragma unroll
        for (int u = 0; u < 4; ++u) {
            async_copy16(gA + k0 + u * 16, &sA[buf][ldst + u * 2048]);
            async_copy16(gB + k0 + u * 16, &sB[buf][ldst + u * 2048]);
        }
    };
    auto compute = [&](int buf) {
#pragma unroll
        for (int kk = 0; kk < 4; ++kk) {
            const int c = kk * 2 + lh;  // k-chunk for this lane-half
            const _Float16* pA = &sA[buf][c * 1024];
            const _Float16* pB = &sB[buf][c * 1024];
            f16x8 af[2], bf[2];
#pragma unroll
            for (int i = 0; i < 2; ++i) {
                af[i] = *(const f16x8*)(pA + aoff0 + i * 256);
                bf[i] = *(const f16x8*)(pB + boff0 + i * 256);
            }
#pragma unroll
            for (int i = 0; i < 2; ++i)
#pragma unroll
                for (int j = 0; j < 2; ++j)
                    acc[i][j] = __builtin_amdgcn_mfma_f32_32x32x16_f16(af[i], bf[j], acc[i][j], 0, 0, 0);
        }
    };

    // prologue: stage tile 0, drain, then pipelined main loop
    stage(0, 0);
    __syncthreads();
    int cur = 0;
    for (int k0 = BK; k0 < K; k0 += BK) {
        stage(cur ^ 1, k0);   // issue next tile into other buffer (in flight)
        compute(cur);         // MFMA on current tile hides the load latency
        __syncthreads();      // one barrier per step: drains vmcnt+lgkm for all
        cur ^= 1;
    }
    compute(cur);  // last tile, no prefetch

#pragma unroll
    for (int i = 0; i < 2; ++i)
#pragma unroll
        for (int j = 0; j < 2; ++j) {
            const int col = n0 + wn + j * 32 + l31;
            const float bv = bias[col];
            const int rbase = m0 + wm + i * 32 + 4 * lh;
            if (OUTMODE == 1) {
                _Float16* C = (_Float16*)Cout;
#pragma unroll
                for (int rr = 0; rr < 16; ++rr) {
                    int row = rbase + (rr & 3) + 8 * (rr >> 2);
                    float v = acc[i][j][rr] + bv;
                    float uu = v * (0.7978845608028654f + 0.0356774081363001f * v * v);
                    float e = __builtin_amdgcn_exp2f(uu * 2.8853900817779268f);
                    float rc = __builtin_amdgcn_rcpf(e + 1.0f);
                    C[(size_t)row * N + col] = (_Float16)(v * (1.0f - rc));
                }
            } else {
                float* C = (float*)Cout;
#pragma unroll
                for (int rr = 0; rr < 16; ++rr) {
                    int row = rbase + (rr & 3) + 8 * (rr >> 2);
                    C[(size_t)row * N + col] = acc[i][j][rr] + bv;
                }
            }
        }
}

extern "C" void kernel_launch(void* const* d_in, const int* in_sizes, int n_in,
                              void* d_out, int out_size, void* d_ws, size_t ws_size,
                              hipStream_t stream) {
    const float* x   = (const float*)d_in[0];
    const float* c0a = (const float*)d_in[1];
    const float* c0b = (const float*)d_in[2];
    const float* c0c = (const float*)d_in[3];
    const float* b0  = (const float*)d_in[4];
    const float* c1a = (const float*)d_in[5];
    const float* c1b = (const float*)d_in[6];
    const float* c1c = (const float*)d_in[7];
    const float* b1  = (const float*)d_in[8];
    float* out = (float*)d_out;

    char* ws = (char*)d_ws;
    _Float16* xh  = (_Float16*)(ws);                          // 16 MB
    _Float16* W0t = (_Float16*)(ws + (size_t)(16u << 20));    //  8 MB
    _Float16* W1t = (_Float16*)(ws + (size_t)(24u << 20));    //  8 MB
    _Float16* h   = (_Float16*)(ws + (size_t)(32u << 20));    // 64 MB

    // 1) fused prep: cast + both weight builds (1408 blocks)
    prep_kernel<<<dim3(1408), dim3(256), 0, stream>>>(
        x, xh, c0a, c0b, c0c, W0t, c1a, c1b, c1c, W1t);
    // 2) h = gelu(x @ W0 + b0)   M=8192 N=4096 K=1024
    gemm32_kernel<1><<<dim3(64, 32), dim3(256), 0, stream>>>(
        xh, W0t, b0, (void*)h, 8192, 4096, 1024);
    // 3) out = h @ W1 + b1       M=8192 N=1024 K=4096
    gemm32_kernel<0><<<dim3(64, 8), dim3(256), 0, stream>>>(
        h, W1t, b1, (void*)out, 8192, 1024, 4096);
}

// Round 2
// 473.508 us; speedup vs baseline: 1.0407x; 1.0407x over previous
//
#include <hip/hip_runtime.h>
#include <math.h>

typedef _Float16 f16x8 __attribute__((ext_vector_type(8)));
typedef _Float16 f16x4 __attribute__((ext_vector_type(4)));
typedef float f32x16 __attribute__((ext_vector_type(16)));

__device__ __forceinline__ void async_copy16(const void* g, void* l) {
    __builtin_amdgcn_global_load_lds(
        (const __attribute__((address_space(1))) void*)g,
        (__attribute__((address_space(3))) void*)l, 16, 0, 0);
}

// ---------------- fused prep: cast x->f16 | build W0t | build W1t ----------------
__global__ __launch_bounds__(256) void prep_kernel(
    const float* __restrict__ x, _Float16* __restrict__ xh,
    const float* __restrict__ c0a, const float* __restrict__ c0b,
    const float* __restrict__ c0c, _Float16* __restrict__ W0t,
    const float* __restrict__ c1a, const float* __restrict__ c1b,
    const float* __restrict__ c1c, _Float16* __restrict__ W1t) {
    __shared__ float G[16384];
    const int b = blockIdx.x, t = threadIdx.x;
    if (b < 1024) {
        const float4* in4 = (const float4*)x;
        f16x4* out4 = (f16x4*)xh;
        const int base = b * 2048 + t;
#pragma unroll
        for (int u = 0; u < 8; ++u) {
            float4 v = in4[base + u * 256];
            f16x4 o;
            o[0] = (_Float16)v.x; o[1] = (_Float16)v.y;
            o[2] = (_Float16)v.z; o[3] = (_Float16)v.w;
            out4[base + u * 256] = o;
        }
    } else if (b < 1280) {
        const int o = (b - 1024) >> 4, p = (b - 1024) & 15;
        // G[q16][r8][j16][k8] = sum_s c0b[r,j,p,s]*c0c[s,k,q]
#pragma unroll
        for (int n = 0; n < 64; ++n) {
            int idx = t + 256 * n;
            int k = idx & 7, j = (idx >> 3) & 15, r = (idx >> 7) & 7, q = idx >> 10;
            float s = 0.f;
#pragma unroll
            for (int ss = 0; ss < 8; ++ss)
                s += c0b[((r * 16 + j) * 16 + p) * 8 + ss] * c0c[(ss * 8 + k) * 16 + q];
            G[idx] = s;
        }
        __syncthreads();
        const int i = t >> 5, j = (t >> 1) & 15, kq = t & 1;
        float a[8];
#pragma unroll
        for (int r = 0; r < 8; ++r) a[r] = c0a[(i * 16 + o) * 8 + r];
        const float4* G4 = (const float4*)G;
#pragma unroll
        for (int q = 0; q < 16; ++q) {
            float4 acc = {0.f, 0.f, 0.f, 0.f};
#pragma unroll
            for (int r = 0; r < 8; ++r) {
                float4 g = G4[q * 256 + r * 32 + j * 2 + kq];
                acc.x += a[r] * g.x; acc.y += a[r] * g.y;
                acc.z += a[r] * g.z; acc.w += a[r] * g.w;
            }
            f16x4 h4;
            h4[0] = (_Float16)acc.x; h4[1] = (_Float16)acc.y;
            h4[2] = (_Float16)acc.z; h4[3] = (_Float16)acc.w;
            *(f16x4*)(W0t + (size_t)((o * 16 + p) * 16 + q) * 1024 + t * 4) = h4;
        }
    } else {
        const int o = (b - 1280) >> 4, p = (b - 1280) & 15;
        // G[q8][r8][j16][k16] = sum_s c1b[r,j,p,s]*c1c[s,k,q]
#pragma unroll
        for (int n = 0; n < 64; ++n) {
            int idx = t + 256 * n;
            int k = idx & 15, j = (idx >> 4) & 15, r = (idx >> 8) & 7, q = idx >> 11;
            float s = 0.f;
#pragma unroll
            for (int ss = 0; ss < 8; ++ss)
                s += c1b[((r * 16 + j) * 16 + p) * 8 + ss] * c1c[(ss * 16 + k) * 8 + q];
            G[idx] = s;
        }
        __syncthreads();
        const int ig = t >> 6, j = (t >> 2) & 15, kq = t & 3;
        float a[4][8];
#pragma unroll
        for (int ii = 0; ii < 4; ++ii)
#pragma unroll
            for (int r = 0; r < 8; ++r) a[ii][r] = c1a[((ig * 4 + ii) * 8 + o) * 8 + r];
        const float4* G4 = (const float4*)G;
#pragma unroll
        for (int q = 0; q < 8; ++q) {
            float4 acc[4] = {{0,0,0,0},{0,0,0,0},{0,0,0,0},{0,0,0,0}};
#pragma unroll
            for (int r = 0; r < 8; ++r) {
                float4 g = G4[q * 512 + r * 64 + j * 4 + kq];
#pragma unroll
                for (int ii = 0; ii < 4; ++ii) {
                    acc[ii].x += a[ii][r] * g.x; acc[ii].y += a[ii][r] * g.y;
                    acc[ii].z += a[ii][r] * g.z; acc[ii].w += a[ii][r] * g.w;
                }
            }
            const size_t rowbase = (size_t)((o * 16 + p) * 8 + q) * 4096;
#pragma unroll
            for (int ii = 0; ii < 4; ++ii) {
                f16x4 h4;
                h4[0] = (_Float16)acc[ii].x; h4[1] = (_Float16)acc[ii].y;
                h4[2] = (_Float16)acc[ii].z; h4[3] = (_Float16)acc[ii].w;
                *(f16x4*)(W1t + rowbase + (ig * 4 + ii) * 256 + j * 16 + kq * 4) = h4;
            }
        }
    }
}

// ---------------- GEMM: C = A(MxK) * Bt(NxK)^T, BK=64, 32x32x16 MFMA ----------------
// Classic proven structure: stage -> barrier -> compute -> barrier (single LDS buf).
// NO block swizzle: natural grid order gives each XCD a resident ~8x8 (m,n)-tile
// window -> A-set + B-set both fit the 4MB XCD L2 (R1: swizzle gave 11x overfetch).
// LDS layout k-chunk-major (conflict-free, verified 0 bank conflicts in R1):
//   elem = c*(ROWS*8) + row*8, c = k/8. Staging: thread t, load u -> slot
//   s = t+256u, row = s&(ROWS-1), chunk = s>>log2(ROWS); dest = s*8 (linear,
//   wave-uniform base + lane*16B as global_load_lds requires).
// BN=128: 4 waves x (64x64), acc[2][2], 16 MFMA/step, LDS 32KB.
// BN=64 (GEMM2 grid-starvation fix): 4 waves x (64x32), acc[2][1], LDS 24KB,
//   grid 64x16=1024 blocks -> 4 blocks/CU instead of 2.
// C/D: col=lane&31, row=(reg&3)+8*(reg>>2)+4*(lane>>5).
// OUTMODE 1: f16 C = gelu(acc+bias);  OUTMODE 0: fp32 C = acc+bias
template <int OUTMODE, int BN>
__global__ __launch_bounds__(256) void gemm32_kernel(
    const _Float16* __restrict__ A, const _Float16* __restrict__ Bt,
    const float* __restrict__ bias, void* __restrict__ Cout,
    int M, int N, int K) {
    constexpr int BK = 64;
    constexpr int BM = 128;
    constexpr int NJ = BN / 64;   // j-tiles per wave (2 or 1)
    constexpr int NBU = BN / 32;  // B staging loads per thread (4 or 2)
    __shared__ alignas(16) _Float16 sA[BM * BK];
    __shared__ alignas(16) _Float16 sB[BN * BK];

    const int t = threadIdx.x, lane = t & 63, w = t >> 6;
    const int m0 = blockIdx.x * BM, n0 = blockIdx.y * BN;
    const int wm = (w & 1) * 64, wn = (w >> 1) * (BN / 2);
    const int l31 = lane & 31, lh = lane >> 5;

    f32x16 acc[2][NJ] = {};

    // staging addresses (row is u-invariant since 256u % ROWS == 0)
    const _Float16* gA = A + (size_t)(m0 + (t & 127)) * K + (t >> 7) * 8;
    const _Float16* gB = Bt + (size_t)(n0 + (t & (BN - 1))) * K + (t / BN) * 8;
    _Float16* lA = sA + t * 8;
    _Float16* lB = sB + t * 8;

    for (int k0 = 0; k0 < K; k0 += BK) {
#pragma unroll
        for (int u = 0; u < 4; ++u)
            async_copy16(gA + k0 + u * 16, lA + u * 2048);
#pragma unroll
        for (int u = 0; u < NBU; ++u)
            async_copy16(gB + k0 + u * (2048 / BN), lB + u * 2048);
        __syncthreads();
#pragma unroll
        for (int kk = 0; kk < 4; ++kk) {
            const int c = kk * 2 + lh;  // k-chunk for this lane-half
            f16x8 af[2], bf[NJ];
#pragma unroll
            for (int i = 0; i < 2; ++i)
                af[i] = *(const f16x8*)(sA + c * (BM * 8) + (wm + i * 32 + l31) * 8);
#pragma unroll
            for (int j = 0; j < NJ; ++j)
                bf[j] = *(const f16x8*)(sB + c * (BN * 8) + (wn + j * 32 + l31) * 8);
#pragma unroll
            for (int i = 0; i < 2; ++i)
#pragma unroll
                for (int j = 0; j < NJ; ++j)
                    acc[i][j] = __builtin_amdgcn_mfma_f32_32x32x16_f16(af[i], bf[j], acc[i][j], 0, 0, 0);
        }
        __syncthreads();
    }

#pragma unroll
    for (int i = 0; i < 2; ++i)
#pragma unroll
        for (int j = 0; j < NJ; ++j) {
            const int col = n0 + wn + j * 32 + l31;
            const float bv = bias[col];
            const int rbase = m0 + wm + i * 32 + 4 * lh;
            if (OUTMODE == 1) {
                _Float16* C = (_Float16*)Cout;
#pragma unroll
                for (int rr = 0; rr < 16; ++rr) {
                    int row = rbase + (rr & 3) + 8 * (rr >> 2);
                    float v = acc[i][j][rr] + bv;
                    float uu = v * (0.7978845608028654f + 0.0356774081363001f * v * v);
                    float e = __builtin_amdgcn_exp2f(uu * 2.8853900817779268f);
                    float rc = __builtin_amdgcn_rcpf(e + 1.0f);
                    C[(size_t)row * N + col] = (_Float16)(v * (1.0f - rc));
                }
            } else {
                float* C = (float*)Cout;
#pragma unroll
                for (int rr = 0; rr < 16; ++rr) {
                    int row = rbase + (rr & 3) + 8 * (rr >> 2);
                    C[(size_t)row * N + col] = acc[i][j][rr] + bv;
                }
            }
        }
}

extern "C" void kernel_launch(void* const* d_in, const int* in_sizes, int n_in,
                              void* d_out, int out_size, void* d_ws, size_t ws_size,
                              hipStream_t stream) {
    const float* x   = (const float*)d_in[0];
    const float* c0a = (const float*)d_in[1];
    const float* c0b = (const float*)d_in[2];
    const float* c0c = (const float*)d_in[3];
    const float* b0  = (const float*)d_in[4];
    const float* c1a = (const float*)d_in[5];
    const float* c1b = (const float*)d_in[6];
    const float* c1c = (const float*)d_in[7];
    const float* b1  = (const float*)d_in[8];
    float* out = (float*)d_out;

    char* ws = (char*)d_ws;
    _Float16* xh  = (_Float16*)(ws);                          // 16 MB
    _Float16* W0t = (_Float16*)(ws + (size_t)(16u << 20));    //  8 MB
    _Float16* W1t = (_Float16*)(ws + (size_t)(24u << 20));    //  8 MB
    _Float16* h   = (_Float16*)(ws + (size_t)(32u << 20));    // 64 MB

    // 1) fused prep: cast + both weight builds (1408 blocks)
    prep_kernel<<<dim3(1408), dim3(256), 0, stream>>>(
        x, xh, c0a, c0b, c0c, W0t, c1a, c1b, c1c, W1t);
    // 2) h = gelu(x @ W0 + b0)   M=8192 N=4096 K=1024
    gemm32_kernel<1, 128><<<dim3(64, 32), dim3(256), 0, stream>>>(
        xh, W0t, b0, (void*)h, 8192, 4096, 1024);
    // 3) out = h @ W1 + b1       M=8192 N=1024 K=4096  (1024 blocks, 4/CU)
    gemm32_kernel<0, 64><<<dim3(64, 16), dim3(256), 0, stream>>>(
        h, W1t, b1, (void*)out, 8192, 1024, 4096);
}

// Round 3
// 377.594 us; speedup vs baseline: 1.3050x; 1.2540x over previous
//
#include <hip/hip_runtime.h>
#include <math.h>

typedef _Float16 f16x8 __attribute__((ext_vector_type(8)));
typedef _Float16 f16x4 __attribute__((ext_vector_type(4)));
typedef float f32x16 __attribute__((ext_vector_type(16)));

__device__ __forceinline__ void async_copy16(const void* g, void* l) {
    __builtin_amdgcn_global_load_lds(
        (const __attribute__((address_space(1))) void*)g,
        (__attribute__((address_space(3))) void*)l, 16, 0, 0);
}

template <int N> __device__ __forceinline__ void vmcnt_wait() {
    if constexpr (N == 8)      asm volatile("s_waitcnt vmcnt(8)" ::: "memory");
    else if constexpr (N == 6) asm volatile("s_waitcnt vmcnt(6)" ::: "memory");
    else if constexpr (N == 4) asm volatile("s_waitcnt vmcnt(4)" ::: "memory");
    else if constexpr (N == 3) asm volatile("s_waitcnt vmcnt(3)" ::: "memory");
    else                       asm volatile("s_waitcnt vmcnt(0)" ::: "memory");
}

// ---------------- fused prep: cast x->f16 | build W0t | build W1t ----------------
__global__ __launch_bounds__(256) void prep_kernel(
    const float* __restrict__ x, _Float16* __restrict__ xh,
    const float* __restrict__ c0a, const float* __restrict__ c0b,
    const float* __restrict__ c0c, _Float16* __restrict__ W0t,
    const float* __restrict__ c1a, const float* __restrict__ c1b,
    const float* __restrict__ c1c, _Float16* __restrict__ W1t) {
    __shared__ float G[16384];
    const int b = blockIdx.x, t = threadIdx.x;
    if (b < 1024) {
        const float4* in4 = (const float4*)x;
        f16x4* out4 = (f16x4*)xh;
        const int base = b * 2048 + t;
#pragma unroll
        for (int u = 0; u < 8; ++u) {
            float4 v = in4[base + u * 256];
            f16x4 o;
            o[0] = (_Float16)v.x; o[1] = (_Float16)v.y;
            o[2] = (_Float16)v.z; o[3] = (_Float16)v.w;
            out4[base + u * 256] = o;
        }
    } else if (b < 1280) {
        const int o = (b - 1024) >> 4, p = (b - 1024) & 15;
        // G[q16][r8][j16][k8] = sum_s c0b[r,j,p,s]*c0c[s,k,q]
#pragma unroll
        for (int n = 0; n < 64; ++n) {
            int idx = t + 256 * n;
            int k = idx & 7, j = (idx >> 3) & 15, r = (idx >> 7) & 7, q = idx >> 10;
            float s = 0.f;
#pragma unroll
            for (int ss = 0; ss < 8; ++ss)
                s += c0b[((r * 16 + j) * 16 + p) * 8 + ss] * c0c[(ss * 8 + k) * 16 + q];
            G[idx] = s;
        }
        __syncthreads();
        const int i = t >> 5, j = (t >> 1) & 15, kq = t & 1;
        float a[8];
#pragma unroll
        for (int r = 0; r < 8; ++r) a[r] = c0a[(i * 16 + o) * 8 + r];
        const float4* G4 = (const float4*)G;
#pragma unroll
        for (int q = 0; q < 16; ++q) {
            float4 acc = {0.f, 0.f, 0.f, 0.f};
#pragma unroll
            for (int r = 0; r < 8; ++r) {
                float4 g = G4[q * 256 + r * 32 + j * 2 + kq];
                acc.x += a[r] * g.x; acc.y += a[r] * g.y;
                acc.z += a[r] * g.z; acc.w += a[r] * g.w;
            }
            f16x4 h4;
            h4[0] = (_Float16)acc.x; h4[1] = (_Float16)acc.y;
            h4[2] = (_Float16)acc.z; h4[3] = (_Float16)acc.w;
            *(f16x4*)(W0t + (size_t)((o * 16 + p) * 16 + q) * 1024 + t * 4) = h4;
        }
    } else {
        const int o = (b - 1280) >> 4, p = (b - 1280) & 15;
        // G[q8][r8][j16][k16] = sum_s c1b[r,j,p,s]*c1c[s,k,q]
#pragma unroll
        for (int n = 0; n < 64; ++n) {
            int idx = t + 256 * n;
            int k = idx & 15, j = (idx >> 4) & 15, r = (idx >> 8) & 7, q = idx >> 11;
            float s = 0.f;
#pragma unroll
            for (int ss = 0; ss < 8; ++ss)
                s += c1b[((r * 16 + j) * 16 + p) * 8 + ss] * c1c[(ss * 16 + k) * 8 + q];
            G[idx] = s;
        }
        __syncthreads();
        const int ig = t >> 6, j = (t >> 2) & 15, kq = t & 3;
        float a[4][8];
#pragma unroll
        for (int ii = 0; ii < 4; ++ii)
#pragma unroll
            for (int r = 0; r < 8; ++r) a[ii][r] = c1a[((ig * 4 + ii) * 8 + o) * 8 + r];
        const float4* G4 = (const float4*)G;
#pragma unroll
        for (int q = 0; q < 8; ++q) {
            float4 acc[4] = {{0,0,0,0},{0,0,0,0},{0,0,0,0},{0,0,0,0}};
#pragma unroll
            for (int r = 0; r < 8; ++r) {
                float4 g = G4[q * 512 + r * 64 + j * 4 + kq];
#pragma unroll
                for (int ii = 0; ii < 4; ++ii) {
                    acc[ii].x += a[ii][r] * g.x; acc[ii].y += a[ii][r] * g.y;
                    acc[ii].z += a[ii][r] * g.z; acc[ii].w += a[ii][r] * g.w;
                }
            }
            const size_t rowbase = (size_t)((o * 16 + p) * 8 + q) * 4096;
#pragma unroll
            for (int ii = 0; ii < 4; ++ii) {
                f16x4 h4;
                h4[0] = (_Float16)acc[ii].x; h4[1] = (_Float16)acc[ii].y;
                h4[2] = (_Float16)acc[ii].z; h4[3] = (_Float16)acc[ii].w;
                *(f16x4*)(W1t + rowbase + (ig * 4 + ii) * 256 + j * 16 + kq * 4) = h4;
            }
        }
    }
}

// ------------- Pipelined GEMM: C = A(MxK) * Bt(NxK)^T, counted-vmcnt 4-slot -------------
// 512 threads = 8 waves (2M x 4N). Sub-tile = 32 k-columns of A(BMx32)+B(BNx32).
// 4 circular LDS slots (slot = s & 3). Step s:
//   stage(s+3)  -> writes slot (s-1)&3: all reads of it retired before the
//                  step-(s-1) barrier (each wave's lgkm waits precede its MFMAs,
//                  which precede barrier arrival) => provably race-free.
//   ds-read 12/8 x b128 + MFMA (compiler inserts precise lgkmcnt waits)
//   vmcnt(2*LPS): retires exactly sub-tile (s+1)'s loads; s+2,s+3 stay IN FLIGHT
//                 across the barrier (T4 - never drain to 0 in steady state).
//   one s_barrier per step.
// Tail: s=NS-3 -> vmcnt(LPS); s=NS-2 -> vmcnt(0); s=NS-1 -> no wait/barrier.
// LDS chunk-major layout (0 bank conflicts, verified R1/R2): within a slot,
//   A elem = chunk*(BM*8) + row*8, chunk = (k-in-subtile)/8.  Stage thread t,
//   load u covers linear slot index (t+512u)*8 => row=(t+512u)&(BM-1),
//   chunk=(t+512u)>>log2(BM); global src = row,k0+chunk*8 (rule 21: linear LDS
//   dest, per-lane global src).  B same with BN=256.
// MFMA 32x32x16_f16 (R2-verified mappings): A-frag m=lane&31, k=(lane>>5)*8+j;
//   C/D col=lane&31, row=(reg&3)+8*(reg>>2)+4*(lane>>5).
// T5: setprio(1) around MFMA cluster (phase-split structure now present).
// OUTMODE 1: f16 C = gelu(acc+bias);  OUTMODE 0: fp32 C = acc+bias
template <int OUTMODE, int BM, int BN>
__global__ __launch_bounds__(512, 2) void gemm_pipe(
    const _Float16* __restrict__ A, const _Float16* __restrict__ Bt,
    const float* __restrict__ bias, void* __restrict__ Cout,
    int M, int N, int K) {
    constexpr int MF = BM / 64;           // m-frags per wave (4 or 2)
    constexpr int NF = BN / 128;          // n-frags per wave (2)
    constexpr int LA = BM / 128;          // A loads/thread/sub-tile (2 or 1)
    constexpr int LB = BN / 128;          // 2
    constexpr int LPS = LA + LB;          // loads per stage (4 or 3)
    constexpr int SLOT = (BM + BN) * 32;  // elements per slot
    constexpr int LOG2BM = (BM == 256 ? 8 : 7);

    __shared__ alignas(16) _Float16 lds[4 * SLOT];

    const int t = threadIdx.x, lane = t & 63, w = t >> 6;
    const int m0 = blockIdx.x * BM, n0 = blockIdx.y * BN;
    const int wm = (w & 1) * (BM / 2), wn = (w >> 1) * (BN / 4);
    const int l31 = lane & 31, lh = lane >> 5;
    const int NS = K >> 5;  // sub-tiles (k-halves of 32)

    f32x16 acc[MF][NF] = {};

    const _Float16* gA = A + (size_t)(m0 + (t & (BM - 1))) * K + ((t >> LOG2BM) * 8);
    const _Float16* gB = Bt + (size_t)(n0 + (t & 255)) * K + ((t >> 8) * 8);

    auto stage = [&](int s) {
        const int slot = s & 3;
        const int k0 = s * 32;
        _Float16* dA = lds + slot * SLOT + t * 8;
#pragma unroll
        for (int u = 0; u < LA; ++u)
            async_copy16(gA + k0 + u * 16, dA + u * 4096);
        _Float16* dB = lds + slot * SLOT + BM * 32 + t * 8;
#pragma unroll
        for (int u = 0; u < LB; ++u)
            async_copy16(gB + k0 + u * 16, dB + u * 4096);
    };

    auto compute = [&](int s) {
        const _Float16* sa = lds + (s & 3) * SLOT;
        const _Float16* sb = sa + BM * 32;
        f16x8 af[MF][2], bf[NF][2];
#pragma unroll
        for (int kf = 0; kf < 2; ++kf) {
            const int ch = kf * 2 + lh;
#pragma unroll
            for (int i = 0; i < MF; ++i)
                af[i][kf] = *(const f16x8*)(sa + ch * (BM * 8) + (wm + i * 32 + l31) * 8);
#pragma unroll
            for (int j = 0; j < NF; ++j)
                bf[j][kf] = *(const f16x8*)(sb + ch * (BN * 8) + (wn + j * 32 + l31) * 8);
        }
        __builtin_amdgcn_s_setprio(1);
#pragma unroll
        for (int i = 0; i < MF; ++i)
#pragma unroll
            for (int j = 0; j < NF; ++j)
#pragma unroll
                for (int kf = 0; kf < 2; ++kf)
                    acc[i][j] = __builtin_amdgcn_mfma_f32_32x32x16_f16(
                        af[i][kf], bf[j][kf], acc[i][j], 0, 0, 0);
        __builtin_amdgcn_s_setprio(0);
    };

    // prologue: fill 3 slots, wait for sub-tile 0 only (tiles 1,2 stay in flight)
    stage(0); stage(1); stage(2);
    vmcnt_wait<2 * LPS>();
    __builtin_amdgcn_s_barrier();

    for (int s = 0; s < NS; ++s) {
        if (s + 3 < NS) stage(s + 3);
        compute(s);
        if (s + 1 < NS) {
            if (s + 3 < NS)      vmcnt_wait<2 * LPS>();
            else if (s + 2 < NS) vmcnt_wait<LPS>();
            else                 vmcnt_wait<0>();
            __builtin_amdgcn_s_barrier();
        }
    }

#pragma unroll
    for (int i = 0; i < MF; ++i)
#pragma unroll
        for (int j = 0; j < NF; ++j) {
            const int col = n0 + wn + j * 32 + l31;
            const float bv = bias[col];
            const int rbase = m0 + wm + i * 32 + 4 * lh;
            if (OUTMODE == 1) {
                _Float16* C = (_Float16*)Cout;
#pragma unroll
                for (int rr = 0; rr < 16; ++rr) {
                    int row = rbase + (rr & 3) + 8 * (rr >> 2);
                    float v = acc[i][j][rr] + bv;
                    float uu = v * (0.7978845608028654f + 0.0356774081363001f * v * v);
                    float e = __builtin_amdgcn_exp2f(uu * 2.8853900817779268f);
                    float rc = __builtin_amdgcn_rcpf(e + 1.0f);
                    C[(size_t)row * N + col] = (_Float16)(v * (1.0f - rc));
                }
            } else {
                float* C = (float*)Cout;
#pragma unroll
                for (int rr = 0; rr < 16; ++rr) {
                    int row = rbase + (rr & 3) + 8 * (rr >> 2);
                    C[(size_t)row * N + col] = acc[i][j][rr] + bv;
                }
            }
        }
}

extern "C" void kernel_launch(void* const* d_in, const int* in_sizes, int n_in,
                              void* d_out, int out_size, void* d_ws, size_t ws_size,
                              hipStream_t stream) {
    const float* x   = (const float*)d_in[0];
    const float* c0a = (const float*)d_in[1];
    const float* c0b = (const float*)d_in[2];
    const float* c0c = (const float*)d_in[3];
    const float* b0  = (const float*)d_in[4];
    const float* c1a = (const float*)d_in[5];
    const float* c1b = (const float*)d_in[6];
    const float* c1c = (const float*)d_in[7];
    const float* b1  = (const float*)d_in[8];
    float* out = (float*)d_out;

    char* ws = (char*)d_ws;
    _Float16* xh  = (_Float16*)(ws);                          // 16 MB
    _Float16* W0t = (_Float16*)(ws + (size_t)(16u << 20));    //  8 MB
    _Float16* W1t = (_Float16*)(ws + (size_t)(24u << 20));    //  8 MB
    _Float16* h   = (_Float16*)(ws + (size_t)(32u << 20));    // 64 MB

    // 1) fused prep: cast + both weight builds (1408 blocks)
    prep_kernel<<<dim3(1408), dim3(256), 0, stream>>>(
        x, xh, c0a, c0b, c0c, W0t, c1a, c1b, c1c, W1t);
    // 2) h = gelu(x @ W0 + b0)   M=8192 N=4096 K=1024   (512 blocks, 256x256)
    gemm_pipe<1, 256, 256><<<dim3(32, 16), dim3(512), 0, stream>>>(
        xh, W0t, b0, (void*)h, 8192, 4096, 1024);
    // 3) out = h @ W1 + b1       M=8192 N=1024 K=4096   (256 blocks, 128x256)
    gemm_pipe<0, 128, 256><<<dim3(64, 4), dim3(512), 0, stream>>>(
        h, W1t, b1, (void*)out, 8192, 1024, 4096);
}

// Round 4
// 376.202 us; speedup vs baseline: 1.3099x; 1.0037x over previous
//
#include <hip/hip_runtime.h>
#include <math.h>

typedef _Float16 f16x8 __attribute__((ext_vector_type(8)));
typedef _Float16 f16x4 __attribute__((ext_vector_type(4)));
typedef float f32x16 __attribute__((ext_vector_type(16)));

__device__ __forceinline__ void async_copy16(const void* g, void* l) {
    __builtin_amdgcn_global_load_lds(
        (const __attribute__((address_space(1))) void*)g,
        (__attribute__((address_space(3))) void*)l, 16, 0, 0);
}

template <int N> __device__ __forceinline__ void vmcnt_wait() {
    if constexpr (N == 8)      asm volatile("s_waitcnt vmcnt(8)" ::: "memory");
    else if constexpr (N == 4) asm volatile("s_waitcnt vmcnt(4)" ::: "memory");
    else                       asm volatile("s_waitcnt vmcnt(0)" ::: "memory");
}

constexpr int ilog2(int x) { return x == 1 ? 0 : 1 + ilog2(x / 2); }

// ---------------- fused prep: cast x->f16 | build W0t | build W1t ----------------
__global__ __launch_bounds__(256) void prep_kernel(
    const float* __restrict__ x, _Float16* __restrict__ xh,
    const float* __restrict__ c0a, const float* __restrict__ c0b,
    const float* __restrict__ c0c, _Float16* __restrict__ W0t,
    const float* __restrict__ c1a, const float* __restrict__ c1b,
    const float* __restrict__ c1c, _Float16* __restrict__ W1t) {
    __shared__ float G[16384];
    const int b = blockIdx.x, t = threadIdx.x;
    if (b < 1024) {
        const float4* in4 = (const float4*)x;
        f16x4* out4 = (f16x4*)xh;
        const int base = b * 2048 + t;
#pragma unroll
        for (int u = 0; u < 8; ++u) {
            float4 v = in4[base + u * 256];
            f16x4 o;
            o[0] = (_Float16)v.x; o[1] = (_Float16)v.y;
            o[2] = (_Float16)v.z; o[3] = (_Float16)v.w;
            out4[base + u * 256] = o;
        }
    } else if (b < 1280) {
        const int o = (b - 1024) >> 4, p = (b - 1024) & 15;
        // G[q16][r8][j16][k8] = sum_s c0b[r,j,p,s]*c0c[s,k,q]
#pragma unroll
        for (int n = 0; n < 64; ++n) {
            int idx = t + 256 * n;
            int k = idx & 7, j = (idx >> 3) & 15, r = (idx >> 7) & 7, q = idx >> 10;
            float s = 0.f;
#pragma unroll
            for (int ss = 0; ss < 8; ++ss)
                s += c0b[((r * 16 + j) * 16 + p) * 8 + ss] * c0c[(ss * 8 + k) * 16 + q];
            G[idx] = s;
        }
        __syncthreads();
        const int i = t >> 5, j = (t >> 1) & 15, kq = t & 1;
        float a[8];
#pragma unroll
        for (int r = 0; r < 8; ++r) a[r] = c0a[(i * 16 + o) * 8 + r];
        const float4* G4 = (const float4*)G;
#pragma unroll
        for (int q = 0; q < 16; ++q) {
            float4 acc = {0.f, 0.f, 0.f, 0.f};
#pragma unroll
            for (int r = 0; r < 8; ++r) {
                float4 g = G4[q * 256 + r * 32 + j * 2 + kq];
                acc.x += a[r] * g.x; acc.y += a[r] * g.y;
                acc.z += a[r] * g.z; acc.w += a[r] * g.w;
            }
            f16x4 h4;
            h4[0] = (_Float16)acc.x; h4[1] = (_Float16)acc.y;
            h4[2] = (_Float16)acc.z; h4[3] = (_Float16)acc.w;
            *(f16x4*)(W0t + (size_t)((o * 16 + p) * 16 + q) * 1024 + t * 4) = h4;
        }
    } else {
        const int o = (b - 1280) >> 4, p = (b - 1280) & 15;
        // G[q8][r8][j16][k16] = sum_s c1b[r,j,p,s]*c1c[s,k,q]
#pragma unroll
        for (int n = 0; n < 64; ++n) {
            int idx = t + 256 * n;
            int k = idx & 15, j = (idx >> 4) & 15, r = (idx >> 8) & 7, q = idx >> 11;
            float s = 0.f;
#pragma unroll
            for (int ss = 0; ss < 8; ++ss)
                s += c1b[((r * 16 + j) * 16 + p) * 8 + ss] * c1c[(ss * 16 + k) * 8 + q];
            G[idx] = s;
        }
        __syncthreads();
        const int ig = t >> 6, j = (t >> 2) & 15, kq = t & 3;
        float a[4][8];
#pragma unroll
        for (int ii = 0; ii < 4; ++ii)
#pragma unroll
            for (int r = 0; r < 8; ++r) a[ii][r] = c1a[((ig * 4 + ii) * 8 + o) * 8 + r];
        const float4* G4 = (const float4*)G;
#pragma unroll
        for (int q = 0; q < 8; ++q) {
            float4 acc[4] = {{0,0,0,0},{0,0,0,0},{0,0,0,0},{0,0,0,0}};
#pragma unroll
            for (int r = 0; r < 8; ++r) {
                float4 g = G4[q * 512 + r * 64 + j * 4 + kq];
#pragma unroll
                for (int ii = 0; ii < 4; ++ii) {
                    acc[ii].x += a[ii][r] * g.x; acc[ii].y += a[ii][r] * g.y;
                    acc[ii].z += a[ii][r] * g.z; acc[ii].w += a[ii][r] * g.w;
                }
            }
            const size_t rowbase = (size_t)((o * 16 + p) * 8 + q) * 4096;
#pragma unroll
            for (int ii = 0; ii < 4; ++ii) {
                f16x4 h4;
                h4[0] = (_Float16)acc[ii].x; h4[1] = (_Float16)acc[ii].y;
                h4[2] = (_Float16)acc[ii].z; h4[3] = (_Float16)acc[ii].w;
                *(f16x4*)(W1t + rowbase + (ig * 4 + ii) * 256 + j * 16 + kq * 4) = h4;
            }
        }
    }
}

// ------------- Phase-split pipelined GEMM (T2+T3+T4+T5), 4-slot counted-vmcnt -------------
// Waves: THREADS/64, arranged 2(m) x WAVES_N(n); per-wave tile WM x WN, frags MF x NF.
//   G1: 512thr 2x4, per-wave 128x64 (MF=4,NF=2), BM=BN=256, LDS 128KB, 1 blk/CU.
//   G2: 256thr 2x2, per-wave  64x64 (MF=2,NF=2), BM=BN=128, LDS  64KB, 2 blk/CU
//       (block-local barriers -> the two blocks overlap each other's stalls).
// K sub-tile = 32 cols, 4 circular LDS slots (slot = tile & 3).
// Per iter t, TWO phases (kf = 0,1), each:
//   { ds_read MF+NF frags (kf's chunks) ; issue 2 staging loads of tile t+2 ;
//     [P1 only: vmcnt(4) -- retires tile t+1's 4 loads, leaves t+2 in flight]
//     raw s_barrier (no drain!) ; setprio(1) ; MF*NF MFMA ; setprio(0) }
// Cross-wave overlap: a wave's MFMAs run while others are still in lgkm waits /
// LDS reads of the same phase (the leading barrier only syncs arrival; lgkm
// waits are per-wave data-dep). vmcnt never drains to 0 in steady state (T4).
// Race safety: stage(t+2) writes slot (t-2)&3, whose reads completed >=2
// barriers ago; tile t+1 readiness is published by P1's vmcnt(4)+barrier.
// LDS chunk-major (0 bank conflicts, verified R1-R3): A elem = ch*(BM*8)+row*8.
// Staging: thread t -> row t&(BM-1), chunks {t>>log2BM} + 2u; dest linear
// (t + THREADS*u)*8 (rule 21: linear LDS dest, per-lane global src).
// MFMA 32x32x16_f16 (R2-verified): A m=lane&31, k=(lane>>5)*8+j;
// C/D col=lane&31, row=(reg&3)+8*(reg>>2)+4*(lane>>5).
template <int OUTMODE, int BM, int BN, int THREADS>
__global__ __launch_bounds__(THREADS, 2) void gemm_pipe(
    const _Float16* __restrict__ A, const _Float16* __restrict__ Bt,
    const float* __restrict__ bias, void* __restrict__ Cout,
    int M, int N, int K) {
    constexpr int WAVES_N = (THREADS / 64) / 2;
    constexpr int WM = BM / 2, WN = BN / WAVES_N;
    constexpr int MF = WM / 32, NF = WN / 32;
    constexpr int LA = BM * 32 / (THREADS * 8);  // A staging loads/thread/tile (=2)
    constexpr int LB = BN * 32 / (THREADS * 8);  // (=2)
    constexpr int SLOT = (BM + BN) * 32;         // elements per slot
    constexpr int L2BM = ilog2(BM), L2BN = ilog2(BN);

    __shared__ alignas(16) _Float16 lds[4 * SLOT];

    const int t = threadIdx.x, lane = t & 63, w = t >> 6;
    const int m0 = blockIdx.x * BM, n0 = blockIdx.y * BN;
    const int wm = (w & 1) * WM, wn = (w >> 1) * WN;
    const int l31 = lane & 31, lh = lane >> 5;
    const int NS = K >> 5;

    f32x16 acc[MF][NF] = {};

    const _Float16* gA = A + (size_t)(m0 + (t & (BM - 1))) * K + ((t >> L2BM) * 8);
    const _Float16* gB = Bt + (size_t)(n0 + (t & (BN - 1))) * K + ((t >> L2BN) * 8);

    auto stageA = [&](int tile) {
        _Float16* d = lds + (tile & 3) * SLOT + t * 8;
        const int k0 = tile * 32;
#pragma unroll
        for (int u = 0; u < LA; ++u)
            async_copy16(gA + k0 + u * 16, d + u * (THREADS * 8));
    };
    auto stageB = [&](int tile) {
        _Float16* d = lds + (tile & 3) * SLOT + BM * 32 + t * 8;
        const int k0 = tile * 32;
#pragma unroll
        for (int u = 0; u < LB; ++u)
            async_copy16(gB + k0 + u * 16, d + u * (THREADS * 8));
    };

    // one phase: read kf's frags, MFMA them (caller places staging/waits/barrier)
    auto read_frags = [&](int tile, int kf, f16x8 af[MF], f16x8 bf[NF]) {
        const _Float16* sa = lds + (tile & 3) * SLOT;
        const _Float16* sb = sa + BM * 32;
        const int ch = kf * 2 + lh;
#pragma unroll
        for (int i = 0; i < MF; ++i)
            af[i] = *(const f16x8*)(sa + ch * (BM * 8) + (wm + i * 32 + l31) * 8);
#pragma unroll
        for (int j = 0; j < NF; ++j)
            bf[j] = *(const f16x8*)(sb + ch * (BN * 8) + (wn + j * 32 + l31) * 8);
    };
    auto do_mfma = [&](f16x8 af[MF], f16x8 bf[NF]) {
        __builtin_amdgcn_s_setprio(1);
#pragma unroll
        for (int i = 0; i < MF; ++i)
#pragma unroll
            for (int j = 0; j < NF; ++j)
                acc[i][j] = __builtin_amdgcn_mfma_f32_32x32x16_f16(
                    af[i], bf[j], acc[i][j], 0, 0, 0);
        __builtin_amdgcn_s_setprio(0);
    };

    // prologue: stage tiles 0,1,2 (12 loads); wait tile 0 only (8 stay in flight)
    stageA(0); stageB(0);
    stageA(1); stageB(1);
    stageA(2); stageB(2);
    vmcnt_wait<8>();
    __builtin_amdgcn_s_barrier();

    for (int tl = 0; tl < NS; ++tl) {
        f16x8 af[MF], bf[NF];
        // ---- phase 0 (kf=0) ----
        read_frags(tl, 0, af, bf);
        if (tl + 2 < NS) stageA(tl + 2);
        __builtin_amdgcn_s_barrier();
        do_mfma(af, bf);
        // ---- phase 1 (kf=1) ----
        read_frags(tl, 1, af, bf);
        if (tl + 2 < NS) stageB(tl + 2);
        if (tl + 2 < NS)      vmcnt_wait<4>();  // retire tile t+1; t+2 in flight
        else if (tl + 1 < NS) vmcnt_wait<0>();  // tail: drain last tile
        __builtin_amdgcn_s_barrier();
        do_mfma(af, bf);
    }

#pragma unroll
    for (int i = 0; i < MF; ++i)
#pragma unroll
        for (int j = 0; j < NF; ++j) {
            const int col = n0 + wn + j * 32 + l31;
            const float bv = bias[col];
            const int rbase = m0 + wm + i * 32 + 4 * lh;
            if (OUTMODE == 1) {
                _Float16* C = (_Float16*)Cout;
#pragma unroll
                for (int rr = 0; rr < 16; ++rr) {
                    int row = rbase + (rr & 3) + 8 * (rr >> 2);
                    float v = acc[i][j][rr] + bv;
                    float uu = v * (0.7978845608028654f + 0.0356774081363001f * v * v);
                    float e = __builtin_amdgcn_exp2f(uu * 2.8853900817779268f);
                    float rc = __builtin_amdgcn_rcpf(e + 1.0f);
                    C[(size_t)row * N + col] = (_Float16)(v * (1.0f - rc));
                }
            } else {
                float* C = (float*)Cout;
#pragma unroll
                for (int rr = 0; rr < 16; ++rr) {
                    int row = rbase + (rr & 3) + 8 * (rr >> 2);
                    C[(size_t)row * N + col] = acc[i][j][rr] + bv;
                }
            }
        }
}

extern "C" void kernel_launch(void* const* d_in, const int* in_sizes, int n_in,
                              void* d_out, int out_size, void* d_ws, size_t ws_size,
                              hipStream_t stream) {
    const float* x   = (const float*)d_in[0];
    const float* c0a = (const float*)d_in[1];
    const float* c0b = (const float*)d_in[2];
    const float* c0c = (const float*)d_in[3];
    const float* b0  = (const float*)d_in[4];
    const float* c1a = (const float*)d_in[5];
    const float* c1b = (const float*)d_in[6];
    const float* c1c = (const float*)d_in[7];
    const float* b1  = (const float*)d_in[8];
    float* out = (float*)d_out;

    char* ws = (char*)d_ws;
    _Float16* xh  = (_Float16*)(ws);                          // 16 MB
    _Float16* W0t = (_Float16*)(ws + (size_t)(16u << 20));    //  8 MB
    _Float16* W1t = (_Float16*)(ws + (size_t)(24u << 20));    //  8 MB
    _Float16* h   = (_Float16*)(ws + (size_t)(32u << 20));    // 64 MB

    // 1) fused prep: cast + both weight builds (1408 blocks)
    prep_kernel<<<dim3(1408), dim3(256), 0, stream>>>(
        x, xh, c0a, c0b, c0c, W0t, c1a, c1b, c1c, W1t);
    // 2) h = gelu(x @ W0 + b0)   M=8192 N=4096 K=1024   (512 blocks, 256x256, 8 waves)
    gemm_pipe<1, 256, 256, 512><<<dim3(32, 16), dim3(512), 0, stream>>>(
        xh, W0t, b0, (void*)h, 8192, 4096, 1024);
    // 3) out = h @ W1 + b1       M=8192 N=1024 K=4096   (512 blocks, 128x128, 2 blk/CU)
    gemm_pipe<0, 128, 128, 256><<<dim3(64, 8), dim3(256), 0, stream>>>(
        h, W1t, b1, (void*)out, 8192, 1024, 4096);
}

// Round 6
// 346.673 us; speedup vs baseline: 1.4214x; 1.0852x over previous
//
#include <hip/hip_runtime.h>
#include <math.h>

typedef _Float16 f16x8 __attribute__((ext_vector_type(8)));
typedef _Float16 f16x4 __attribute__((ext_vector_type(4)));
typedef float f32x16 __attribute__((ext_vector_type(16)));

__device__ __forceinline__ void async_copy16(const void* g, void* l) {
    __builtin_amdgcn_global_load_lds(
        (const __attribute__((address_space(1))) void*)g,
        (__attribute__((address_space(3))) void*)l, 16, 0, 0);
}

template <int N> __device__ __forceinline__ void vmcnt_wait() {
    if constexpr (N == 8)      asm volatile("s_waitcnt vmcnt(8)" ::: "memory");
    else if constexpr (N == 6) asm volatile("s_waitcnt vmcnt(6)" ::: "memory");
    else if constexpr (N == 4) asm volatile("s_waitcnt vmcnt(4)" ::: "memory");
    else if constexpr (N == 3) asm volatile("s_waitcnt vmcnt(3)" ::: "memory");
    else                       asm volatile("s_waitcnt vmcnt(0)" ::: "memory");
}

constexpr int ilog2(int x) { return x == 1 ? 0 : 1 + ilog2(x / 2); }

// ---------------- fused prep: cast x->f16 | build W0t | build W1t ----------------
// G-build: thread -> fixed (q,k), half h=t>>7 splits the rj-range; 8 c-core
// values hoisted to registers; rj loop wave-uniform so the b-core float4 loads
// are uniform (scalarizable). Index algebra verified == R4 original (R5 audit).
__global__ __launch_bounds__(256) void prep_kernel(
    const float* __restrict__ x, _Float16* __restrict__ xh,
    const float* __restrict__ c0a, const float* __restrict__ c0b,
    const float* __restrict__ c0c, _Float16* __restrict__ W0t,
    const float* __restrict__ c1a, const float* __restrict__ c1b,
    const float* __restrict__ c1c, _Float16* __restrict__ W1t) {
    __shared__ float G[16384];
    const int b = blockIdx.x, t = threadIdx.x;
    if (b < 1024) {
        const float4* in4 = (const float4*)x;
        f16x4* out4 = (f16x4*)xh;
        const int base = b * 2048 + t;
#pragma unroll
        for (int u = 0; u < 8; ++u) {
            float4 v = in4[base + u * 256];
            f16x4 o;
            o[0] = (_Float16)v.x; o[1] = (_Float16)v.y;
            o[2] = (_Float16)v.z; o[3] = (_Float16)v.w;
            out4[base + u * 256] = o;
        }
    } else if (b < 1280) {
        const int o = (b - 1024) >> 4, p = (b - 1024) & 15;
        // G[q16][r8][j16][k8] = sum_ss c0b[r,j,p,ss]*c0c[ss,k,q]; idx=q*1024+rj*8+k
        {
            const int h = t >> 7, qk = t & 127, q = qk >> 3, k = qk & 7;
            float cr[8];
#pragma unroll
            for (int ss = 0; ss < 8; ++ss) cr[ss] = c0c[(ss * 8 + k) * 16 + q];
            for (int rj = h * 64; rj < h * 64 + 64; ++rj) {
                const float4* b4 = (const float4*)(c0b + (rj * 16 + p) * 8);
                float4 b0 = b4[0], b1 = b4[1];
                float s = b0.x * cr[0] + b0.y * cr[1] + b0.z * cr[2] + b0.w * cr[3]
                        + b1.x * cr[4] + b1.y * cr[5] + b1.z * cr[6] + b1.w * cr[7];
                G[q * 1024 + rj * 8 + k] = s;
            }
        }
        __syncthreads();
        const int i = t >> 5, j = (t >> 1) & 15, kq = t & 1;
        float a[8];
#pragma unroll
        for (int r = 0; r < 8; ++r) a[r] = c0a[(i * 16 + o) * 8 + r];
        const float4* G4 = (const float4*)G;
#pragma unroll
        for (int q = 0; q < 16; ++q) {
            float4 acc = {0.f, 0.f, 0.f, 0.f};
#pragma unroll
            for (int r = 0; r < 8; ++r) {
                float4 g = G4[q * 256 + r * 32 + j * 2 + kq];
                acc.x += a[r] * g.x; acc.y += a[r] * g.y;
                acc.z += a[r] * g.z; acc.w += a[r] * g.w;
            }
            f16x4 h4;
            h4[0] = (_Float16)acc.x; h4[1] = (_Float16)acc.y;
            h4[2] = (_Float16)acc.z; h4[3] = (_Float16)acc.w;
            *(f16x4*)(W0t + (size_t)((o * 16 + p) * 16 + q) * 1024 + t * 4) = h4;
        }
    } else {
        const int o = (b - 1280) >> 4, p = (b - 1280) & 15;
        // G[q8][r8][j16][k16] = sum_ss c1b[r,j,p,ss]*c1c[ss,k,q]; idx=q*2048+rj*16+k
        {
            const int h = t >> 7, qk = t & 127, q = qk >> 4, k = qk & 15;
            float cr[8];
#pragma unroll
            for (int ss = 0; ss < 8; ++ss) cr[ss] = c1c[(ss * 16 + k) * 8 + q];
            for (int rj = h * 64; rj < h * 64 + 64; ++rj) {
                const float4* b4 = (const float4*)(c1b + (rj * 16 + p) * 8);
                float4 b0 = b4[0], b1 = b4[1];
                float s = b0.x * cr[0] + b0.y * cr[1] + b0.z * cr[2] + b0.w * cr[3]
                        + b1.x * cr[4] + b1.y * cr[5] + b1.z * cr[6] + b1.w * cr[7];
                G[q * 2048 + rj * 16 + k] = s;
            }
        }
        __syncthreads();
        const int ig = t >> 6, j = (t >> 2) & 15, kq = t & 3;
        float a[4][8];
#pragma unroll
        for (int ii = 0; ii < 4; ++ii)
#pragma unroll
            for (int r = 0; r < 8; ++r) a[ii][r] = c1a[((ig * 4 + ii) * 8 + o) * 8 + r];
        const float4* G4 = (const float4*)G;
#pragma unroll
        for (int q = 0; q < 8; ++q) {
            float4 acc[4] = {{0,0,0,0},{0,0,0,0},{0,0,0,0},{0,0,0,0}};
#pragma unroll
            for (int r = 0; r < 8; ++r) {
                float4 g = G4[q * 512 + r * 64 + j * 4 + kq];
#pragma unroll
                for (int ii = 0; ii < 4; ++ii) {
                    acc[ii].x += a[ii][r] * g.x; acc[ii].y += a[ii][r] * g.y;
                    acc[ii].z += a[ii][r] * g.z; acc[ii].w += a[ii][r] * g.w;
                }
            }
            const size_t rowbase = (size_t)((o * 16 + p) * 8 + q) * 4096;
#pragma unroll
            for (int ii = 0; ii < 4; ++ii) {
                f16x4 h4;
                h4[0] = (_Float16)acc[ii].x; h4[1] = (_Float16)acc[ii].y;
                h4[2] = (_Float16)acc[ii].z; h4[3] = (_Float16)acc[ii].w;
                *(f16x4*)(W1t + rowbase + (ig * 4 + ii) * 256 + j * 16 + kq * 4) = h4;
            }
        }
    }
}

// ------- Pipelined GEMM: BK=64 K-tiles, 2 phases/tile, per-phase counted vmcnt -------
// 512 thr = 8 waves (2m x 4n); per-wave WM x WN (G1 128x64: 16 MFMA/phase;
// G2 64x64: 8 MFMA/phase).
// Phase (tile tl, p): read_frags(k-half p) ; stage half p of tile tl+1 ;
//   vmcnt(LPS) [retires the half read NEXT phase, leaves this phase's LPS
//   in flight - T4] ; s_barrier ; setprio(1) MFMAs setprio(0).
// Race ledger (R5 audit): barrier(u) publishes the half staged at phase u-1,
//   read at phase u+1. Stage(u) writes (tl+1,p) buf^1; latest prior reads of
//   that region were phase u-2's, completed before mfma(u-2) < barrier(u-1)
//   < stage(u). Tail: last tile's p0 drains vmcnt(0).
// STAGING MATH (R5 bug was here): thread t, load u -> LDS slot s = t+512u,
//   row = s & (BM-1) (u-invariant), ch_local = s >> L2BM = (t>>L2BM) + u*(512>>L2BM)
//   => global k advances u * (4096/BM) ELEMENTS. R5 had u*((4096/BM)*8) = x8 too far.
// LDS chunk-major => 32 lanes x 16B contiguous per ds_read, 0 bank conflicts.
// MFMA mappings (R2-verified): A m=lane&31 k=(lane>>5)*8+j; C/D col=lane&31,
// row=(reg&3)+8*(reg>>2)+4*(lane>>5).
template <int OUTMODE, int BM, int BN>
__global__ __launch_bounds__(512, 2) void gemm_pipe(
    const _Float16* __restrict__ A, const _Float16* __restrict__ Bt,
    const float* __restrict__ bias, void* __restrict__ Cout,
    int M, int N, int K) {
    constexpr int WM = BM / 2, WN = BN / 4;
    constexpr int MF = WM / 32, NF = WN / 32;
    constexpr int LAH = BM / 128;        // A gload_lds per thread per half (2|1)
    constexpr int LBH = BN / 128;        // 2
    constexpr int LPS = LAH + LBH;       // loads per phase (4|3)
    constexpr int BUFE = (BM + BN) * 64; // elems per buffer
    constexpr int L2BM = ilog2(BM);

    __shared__ alignas(16) _Float16 lds[2 * BUFE];

    const int t = threadIdx.x, lane = t & 63, w = t >> 6;
    const int m0 = blockIdx.x * BM, n0 = blockIdx.y * BN;
    const int wm = (w & 1) * WM, wn = (w >> 1) * WN;
    const int l31 = lane & 31, lh = lane >> 5;
    const int NS = K >> 6;  // BK=64 tiles

    f32x16 acc[MF][NF] = {};

    const _Float16* gA = A + (size_t)(m0 + (t & (BM - 1))) * K + ((t >> L2BM) * 8);
    const _Float16* gB = Bt + (size_t)(n0 + (t & 255)) * K + ((t >> 8) * 8);

    auto stage_half = [&](int tile, int h) {
        const int buf = tile & 1;
        const int k0 = tile * 64 + h * 32;
        _Float16* dA = lds + buf * BUFE + h * (BM * 32) + t * 8;
#pragma unroll
        for (int u = 0; u < LAH; ++u)
            async_copy16(gA + k0 + u * (4096 / BM), dA + u * 4096);  // u*16 elems @BM=256
        _Float16* dB = lds + buf * BUFE + BM * 64 + h * (BN * 32) + t * 8;
#pragma unroll
        for (int u = 0; u < LBH; ++u)
            async_copy16(gB + k0 + u * (4096 / BN), dB + u * 4096);  // u*16 elems @BN=256
    };

    auto read_frags = [&](int buf, int p, f16x8 af[MF][2], f16x8 bf[NF][2]) {
        const _Float16* sa = lds + buf * BUFE;
        const _Float16* sb = sa + BM * 64;
#pragma unroll
        for (int q = 0; q < 2; ++q) {
            const int ch = 4 * p + 2 * q + lh;
#pragma unroll
            for (int i = 0; i < MF; ++i)
                af[i][q] = *(const f16x8*)(sa + ch * (BM * 8) + (wm + i * 32 + l31) * 8);
#pragma unroll
            for (int j = 0; j < NF; ++j)
                bf[j][q] = *(const f16x8*)(sb + ch * (BN * 8) + (wn + j * 32 + l31) * 8);
        }
    };
    auto do_mfma = [&](f16x8 af[MF][2], f16x8 bf[NF][2]) {
        __builtin_amdgcn_s_setprio(1);
#pragma unroll
        for (int q = 0; q < 2; ++q)
#pragma unroll
            for (int i = 0; i < MF; ++i)
#pragma unroll
                for (int j = 0; j < NF; ++j)
                    acc[i][j] = __builtin_amdgcn_mfma_f32_32x32x16_f16(
                        af[i][q], bf[j][q], acc[i][j], 0, 0, 0);
        __builtin_amdgcn_s_setprio(0);
    };

    // prologue: stage both halves of tile 0; retire half0 (half1 stays in flight)
    stage_half(0, 0);
    stage_half(0, 1);
    vmcnt_wait<LPS>();
    __builtin_amdgcn_s_barrier();

    for (int tl = 0; tl < NS; ++tl) {
#pragma unroll
        for (int p = 0; p < 2; ++p) {
            f16x8 af[MF][2], bf[NF][2];
            read_frags(tl & 1, p, af, bf);
            if (tl + 1 < NS) stage_half(tl + 1, p);
            if (tl + 1 < NS) {
                vmcnt_wait<LPS>();
                __builtin_amdgcn_s_barrier();
            } else if (p == 0) {
                vmcnt_wait<0>();  // retire final half for the last phase's reads
                __builtin_amdgcn_s_barrier();
            }
            do_mfma(af, bf);
        }
    }

#pragma unroll
    for (int i = 0; i < MF; ++i)
#pragma unroll
        for (int j = 0; j < NF; ++j) {
            const int col = n0 + wn + j * 32 + l31;
            const float bv = bias[col];
            const int rbase = m0 + wm + i * 32 + 4 * lh;
            if (OUTMODE == 1) {
                _Float16* C = (_Float16*)Cout;
#pragma unroll
                for (int rr = 0; rr < 16; ++rr) {
                    int row = rbase + (rr & 3) + 8 * (rr >> 2);
                    float v = acc[i][j][rr] + bv;
                    float uu = v * (0.7978845608028654f + 0.0356774081363001f * v * v);
                    float e = __builtin_amdgcn_exp2f(uu * 2.8853900817779268f);
                    float rc = __builtin_amdgcn_rcpf(e + 1.0f);
                    C[(size_t)row * N + col] = (_Float16)(v * (1.0f - rc));
                }
            } else {
                float* C = (float*)Cout;
#pragma unroll
                for (int rr = 0; rr < 16; ++rr) {
                    int row = rbase + (rr & 3) + 8 * (rr >> 2);
                    C[(size_t)row * N + col] = acc[i][j][rr] + bv;
                }
            }
        }
}

extern "C" void kernel_launch(void* const* d_in, const int* in_sizes, int n_in,
                              void* d_out, int out_size, void* d_ws, size_t ws_size,
                              hipStream_t stream) {
    const float* x   = (const float*)d_in[0];
    const float* c0a = (const float*)d_in[1];
    const float* c0b = (const float*)d_in[2];
    const float* c0c = (const float*)d_in[3];
    const float* b0  = (const float*)d_in[4];
    const float* c1a = (const float*)d_in[5];
    const float* c1b = (const float*)d_in[6];
    const float* c1c = (const float*)d_in[7];
    const float* b1  = (const float*)d_in[8];
    float* out = (float*)d_out;

    char* ws = (char*)d_ws;
    _Float16* xh  = (_Float16*)(ws);                          // 16 MB
    _Float16* W0t = (_Float16*)(ws + (size_t)(16u << 20));    //  8 MB
    _Float16* W1t = (_Float16*)(ws + (size_t)(24u << 20));    //  8 MB
    _Float16* h   = (_Float16*)(ws + (size_t)(32u << 20));    // 64 MB

    // 1) fused prep: cast + both weight builds (1408 blocks)
    prep_kernel<<<dim3(1408), dim3(256), 0, stream>>>(
        x, xh, c0a, c0b, c0c, W0t, c1a, c1b, c1c, W1t);
    // 2) h = gelu(x @ W0 + b0)   M=8192 N=4096 K=1024   (512 blocks, 256x256)
    gemm_pipe<1, 256, 256><<<dim3(32, 16), dim3(512), 0, stream>>>(
        xh, W0t, b0, (void*)h, 8192, 4096, 1024);
    // 3) out = h @ W1 + b1       M=8192 N=1024 K=4096   (256 blocks, 128x256, 1/CU)
    gemm_pipe<0, 128, 256><<<dim3(64, 4), dim3(512), 0, stream>>>(
        h, W1t, b1, (void*)out, 8192, 1024, 4096);
}